// Round 1
// baseline (2141.250 us; speedup 1.0000x reference)
//
#include <hip/hip_runtime.h>
#include <hip/hip_bf16.h>

#define BB_ 16
#define TT_ 96
#define NN 512
#define DD 128
#define MM 1196
#define KK 8
#define HID 65536
#define TP 97
#define TPAD 128

__device__ __forceinline__ float gelu_exact(float x) {
    return 0.5f * x * (1.0f + erff(x * 0.70710678118654752f));
}

// K1: depthwise conv (cross-correlation, pad 6/6) + bias + gelu -> xc (B, N, TPAD), zeros for t>=97
__global__ __launch_bounds__(256) void k1_conv(const float* __restrict__ x,
                                               const float* __restrict__ dw_w,
                                               const float* __restrict__ dw_b,
                                               float* __restrict__ xc) {
    int b = blockIdx.y, n0 = blockIdx.x * 64;
    __shared__ float xs[96][64];
    __shared__ float ws[64][12];
    __shared__ float bs[64];
    int tid = threadIdx.x;
    for (int j = tid; j < 96 * 64; j += 256) {
        int t = j / 64, n = j % 64;
        xs[t][n] = x[(size_t)(b * TT_ + t) * NN + n0 + n];
    }
    for (int j = tid; j < 64 * 12; j += 256) {
        int n = j / 12, k = j % 12;
        ws[n][k] = dw_w[(size_t)(n0 + n) * 12 + k];
    }
    if (tid < 64) bs[tid] = dw_b[n0 + tid];
    __syncthreads();
    int n = tid % 64, g = tid / 64;
    for (int t = g; t < TP; t += 4) {
        float acc = bs[n];
        #pragma unroll
        for (int k = 0; k < 12; ++k) {
            int ti = t - 6 + k;
            if (ti >= 0 && ti < 96) acc += xs[ti][n] * ws[n][k];
        }
        xc[((size_t)b * NN + n0 + n) * TPAD + t] = gelu_exact(acc);
    }
    for (int t = TP + g; t < TPAD; t += 4)
        xc[((size_t)b * NN + n0 + n) * TPAD + t] = 0.0f;
}

// K2: per b: C = pw_w(65536x512) @ xc_b(512x128pad); gelu(C + pw_b); mean over t<97 -> q_pre (B, HID)
__global__ __launch_bounds__(256) void k2_pw(const float* __restrict__ pw_w,
                                             const float* __restrict__ pw_b,
                                             const float* __restrict__ xc,
                                             float* __restrict__ q_pre) {
    int b = blockIdx.y;
    int o0 = blockIdx.x * 128;
    __shared__ float As[16][128];
    __shared__ float Bs[16][128];
    __shared__ float red[128][16];
    int tid = threadIdx.x;
    int tx = tid % 16, ty = tid / 16;
    float acc[8][8];
    #pragma unroll
    for (int r = 0; r < 8; ++r)
        #pragma unroll
        for (int c = 0; c < 8; ++c) acc[r][c] = 0.f;
    const float* xcb = xc + (size_t)b * NN * TPAD;
    for (int i0 = 0; i0 < 512; i0 += 16) {
        {   // A tile: pw_w[o0+r][i0+c] -> As[c][r]
            int r = tid >> 1, half = tid & 1;
            const float* src = pw_w + (size_t)(o0 + r) * 512 + i0 + half * 8;
            float4 v0 = *(const float4*)(src);
            float4 v1 = *(const float4*)(src + 4);
            int cb = half * 8;
            As[cb + 0][r] = v0.x; As[cb + 1][r] = v0.y; As[cb + 2][r] = v0.z; As[cb + 3][r] = v0.w;
            As[cb + 4][r] = v1.x; As[cb + 5][r] = v1.y; As[cb + 6][r] = v1.z; As[cb + 7][r] = v1.w;
        }
        {   // B tile: xc[b][i0+c][t] -> Bs[c][t]
            int c = tid >> 4, t0 = (tid & 15) * 8;
            const float* src = xcb + (size_t)(i0 + c) * TPAD + t0;
            float4 v0 = *(const float4*)(src);
            float4 v1 = *(const float4*)(src + 4);
            *(float4*)&Bs[c][t0] = v0;
            *(float4*)&Bs[c][t0 + 4] = v1;
        }
        __syncthreads();
        #pragma unroll
        for (int kk = 0; kk < 16; ++kk) {
            float a[8], bb[8];
            *(float4*)&a[0] = *(float4*)&As[kk][ty * 8];
            *(float4*)&a[4] = *(float4*)&As[kk][ty * 8 + 4];
            *(float4*)&bb[0] = *(float4*)&Bs[kk][tx * 8];
            *(float4*)&bb[4] = *(float4*)&Bs[kk][tx * 8 + 4];
            #pragma unroll
            for (int r = 0; r < 8; ++r)
                #pragma unroll
                for (int c = 0; c < 8; ++c) acc[r][c] += a[r] * bb[c];
        }
        __syncthreads();
    }
    // epilogue: gelu + masked mean over t
    float part[8];
    #pragma unroll
    for (int r = 0; r < 8; ++r) {
        int o = o0 + ty * 8 + r;
        float bias = pw_b[o];
        float s = 0.f;
        #pragma unroll
        for (int c = 0; c < 8; ++c) {
            int t = tx * 8 + c;
            if (t < TP) s += gelu_exact(acc[r][c] + bias);
        }
        part[r] = s;
    }
    #pragma unroll
    for (int r = 0; r < 8; ++r) red[ty * 8 + r][tx] = part[r];
    __syncthreads();
    if (tid < 128) {
        float s = 0.f;
        #pragma unroll
        for (int j = 0; j < 16; ++j) s += red[tid][j];
        q_pre[(size_t)b * HID + o0 + tid] = s * (1.0f / 97.0f);
    }
}

// K3: LayerNorm over D=128 per row; writes q (second output)
__global__ __launch_bounds__(256) void k3_ln(const float* __restrict__ q_pre,
                                             const float* __restrict__ g,
                                             const float* __restrict__ beta,
                                             float* __restrict__ qout) {
    int row = blockIdx.x * 4 + (threadIdx.x >> 6);
    int lane = threadIdx.x & 63;
    const float* src = q_pre + (size_t)row * 128;
    float v0 = src[lane], v1 = src[lane + 64];
    float s = v0 + v1;
    #pragma unroll
    for (int m = 32; m >= 1; m >>= 1) s += __shfl_xor(s, m, 64);
    float mu = s * (1.f / 128.f);
    float d0 = v0 - mu, d1 = v1 - mu;
    float vs = d0 * d0 + d1 * d1;
    #pragma unroll
    for (int m = 32; m >= 1; m >>= 1) vs += __shfl_xor(vs, m, 64);
    float rstd = rsqrtf(vs * (1.f / 128.f) + 1e-5f);
    qout[(size_t)row * 128 + lane] = d0 * rstd * g[lane] + beta[lane];
    qout[(size_t)row * 128 + lane + 64] = d1 * rstd * g[lane + 64] + beta[lane + 64];
}

// K3b: per-b L2 norm of q (65536 elems)
__global__ __launch_bounds__(256) void k3b_qnorm(const float* __restrict__ q, float* __restrict__ qnorm) {
    int b = blockIdx.x;
    const float* src = q + (size_t)b * HID;
    float s = 0.f;
    for (int i = threadIdx.x * 4; i < HID; i += 256 * 4) {
        float4 v = *(const float4*)(src + i);
        s += v.x * v.x + v.y * v.y + v.z * v.z + v.w * v.w;
    }
    #pragma unroll
    for (int m = 32; m >= 1; m >>= 1) s += __shfl_xor(s, m, 64);
    __shared__ float red[4];
    if ((threadIdx.x & 63) == 0) red[threadIdx.x >> 6] = s;
    __syncthreads();
    if (threadIdx.x == 0) qnorm[b] = sqrtf(red[0] + red[1] + red[2] + red[3]);
}

// K4: fused (mem row sumsq) + (16 q-dots). m-tile=4, K-split=4 -> deterministic partials in ws
__global__ __launch_bounds__(256) void k4_sim(const float* __restrict__ mem,
                                              const float* __restrict__ q,
                                              float* __restrict__ sim_part,
                                              float* __restrict__ nrm_part) {
    int m0 = blockIdx.x * 4;
    int isp = blockIdx.y;
    int tid = threadIdx.x;
    float acc[4][16];
    float nr[4] = {0.f, 0.f, 0.f, 0.f};
    #pragma unroll
    for (int a = 0; a < 4; ++a)
        #pragma unroll
        for (int c = 0; c < 16; ++c) acc[a][c] = 0.f;
    int ibase = isp * 16384;
    for (int it = 0; it < 16; ++it) {
        int i = ibase + (it * 256 + tid) * 4;
        float4 mv[4];
        #pragma unroll
        for (int a = 0; a < 4; ++a) {
            mv[a] = *(const float4*)(mem + (size_t)(m0 + a) * HID + i);
            nr[a] += mv[a].x * mv[a].x + mv[a].y * mv[a].y + mv[a].z * mv[a].z + mv[a].w * mv[a].w;
        }
        #pragma unroll
        for (int c = 0; c < 16; ++c) {
            float4 qv = *(const float4*)(q + (size_t)c * HID + i);
            #pragma unroll
            for (int a = 0; a < 4; ++a)
                acc[a][c] += mv[a].x * qv.x + mv[a].y * qv.y + mv[a].z * qv.z + mv[a].w * qv.w;
        }
    }
    __shared__ float red[4][68];
    int wv = tid >> 6, lane = tid & 63;
    #pragma unroll
    for (int a = 0; a < 4; ++a)
        for (int c = 0; c < 17; ++c) {
            float v = (c < 16) ? acc[a][c] : nr[a];
            #pragma unroll
            for (int m = 32; m >= 1; m >>= 1) v += __shfl_xor(v, m, 64);
            if (lane == 0) red[wv][a * 17 + c] = v;
        }
    __syncthreads();
    if (tid < 68) {
        float v = red[0][tid] + red[1][tid] + red[2][tid] + red[3][tid];
        int a = tid / 17, r = tid % 17;
        if (r < 16) sim_part[((size_t)isp * 16 + r) * MM + m0 + a] = v;
        else nrm_part[(size_t)isp * MM + m0 + a] = v;
    }
}

// K5: combine partials, normalize, season mask, diversity scale, top-8 (tie -> lower index)
__global__ __launch_bounds__(256) void k5_topk(const float* __restrict__ sim_part,
                                               const float* __restrict__ nrm_part,
                                               const float* __restrict__ qnorm,
                                               const int* __restrict__ season_q,
                                               const float* __restrict__ year_q,
                                               const int* __restrict__ mem_season,
                                               const float* __restrict__ mem_year,
                                               int* __restrict__ topk) {
    int b = blockIdx.x;
    int tid = threadIdx.x;
    __shared__ float sadj[MM];
    float nq = fmaxf(qnorm[b], 1e-12f);
    int sq = season_q[b];
    float yq = year_q[b];
    for (int m = tid; m < MM; m += 256) {
        float dot = 0.f, ns = 0.f;
        #pragma unroll
        for (int p = 0; p < 4; ++p) {
            dot += sim_part[((size_t)p * 16 + b) * MM + m];
            ns += nrm_part[(size_t)p * MM + m];
        }
        float nm = fmaxf(sqrtf(ns), 1e-12f);
        float s = dot / (nq * nm);
        if (mem_season[m] != sq) s = -10000.0f;
        float dy = fabsf(yq - mem_year[m]);
        float dv = 1.0f - expf(-dy * 0.5f);
        s *= (0.5f + 0.5f * dv);
        sadj[m] = s;
    }
    __syncthreads();
    __shared__ float rv[4];
    __shared__ int ri[4];
    for (int it = 0; it < 8; ++it) {
        float bv = -INFINITY;
        int bi = -1;
        for (int m = tid; m < MM; m += 256) {
            float v = sadj[m];
            if (v > bv || (v == bv && bi >= 0 && m < bi)) { bv = v; bi = m; }
        }
        #pragma unroll
        for (int msk = 32; msk >= 1; msk >>= 1) {
            float ov = __shfl_xor(bv, msk, 64);
            int oi = __shfl_xor(bi, msk, 64);
            if (oi >= 0 && (ov > bv || (ov == bv && (bi < 0 || oi < bi)))) { bv = ov; bi = oi; }
        }
        int lane = tid & 63, wv = tid >> 6;
        if (lane == 0) { rv[wv] = bv; ri[wv] = bi; }
        __syncthreads();
        if (tid == 0) {
            float fv = rv[0]; int fi = ri[0];
            for (int w = 1; w < 4; ++w)
                if (ri[w] >= 0 && (rv[w] > fv || (rv[w] == fv && (fi < 0 || ri[w] < fi)))) { fv = rv[w]; fi = ri[w]; }
            topk[b * KK + it] = fi;
            sadj[fi] = -INFINITY;
        }
        __syncthreads();
    }
}

// K6: fused attention: gather kv, q/k/v projections, softmax over K=8, ctx, out_proj, proj
__global__ __launch_bounds__(256) void k6_attn(const float* __restrict__ mem,
                                               const float* __restrict__ q,
                                               const int* __restrict__ topk,
                                               const float* __restrict__ in_w,
                                               const float* __restrict__ in_b,
                                               const float* __restrict__ ow,
                                               const float* __restrict__ ob,
                                               const float* __restrict__ pw,
                                               const float* __restrict__ pb,
                                               float* __restrict__ out) {
    int b = blockIdx.y;
    int n0 = blockIdx.x * 4;
    int tid = threadIdx.x;
    __shared__ float kv_s[4][8][128];
    __shared__ float kh_s[4][8][128];
    __shared__ float vh_s[4][8][128];
    __shared__ float qin_s[4][128];
    __shared__ float qh_s[4][128];
    __shared__ float ctx_s[4][128];
    __shared__ float o1_s[4][128];
    __shared__ int idx_s[8];
    if (tid < 8) idx_s[tid] = topk[b * 8 + tid];
    __syncthreads();
    for (int j = tid; j < 4 * 8 * 32; j += 256) {
        int n = j >> 8;
        int k = (j >> 5) & 7;
        int d4 = (j & 31) * 4;
        float4 v = *(const float4*)(mem + (size_t)idx_s[k] * HID + (size_t)(n0 + n) * 128 + d4);
        *(float4*)&kv_s[n][k][d4] = v;
    }
    for (int j = tid; j < 4 * 32; j += 256) {
        int n = j >> 5;
        int d4 = (j & 31) * 4;
        *(float4*)&qin_s[n][d4] = *(const float4*)(q + (size_t)(b * NN + n0 + n) * 128 + d4);
    }
    __syncthreads();
    {   // qh
        int d = tid & 127, half = tid >> 7;
        for (int n2 = 0; n2 < 2; ++n2) {
            int n = half * 2 + n2;
            float a = in_b[d];
            const float* wr = in_w + (size_t)d * 128;
            #pragma unroll
            for (int i = 0; i < 128; i += 4) {
                float4 w4 = *(const float4*)(wr + i);
                a += w4.x * qin_s[n][i] + w4.y * qin_s[n][i + 1] + w4.z * qin_s[n][i + 2] + w4.w * qin_s[n][i + 3];
            }
            qh_s[n][d] = a;
        }
    }
    {   // kh, vh
        int d = tid & 127, layer = tid >> 7;
        float ak[16], av[16];
        #pragma unroll
        for (int p = 0; p < 16; ++p) { ak[p] = in_b[128 + d]; av[p] = in_b[256 + d]; }
        const float* wkr = in_w + (size_t)(128 + d) * 128;
        const float* wvr = in_w + (size_t)(256 + d) * 128;
        for (int i = 0; i < 128; i += 4) {
            float4 wk4 = *(const float4*)(wkr + i);
            float4 wv4 = *(const float4*)(wvr + i);
            #pragma unroll
            for (int p = 0; p < 16; ++p) {
                int pg = layer * 16 + p;
                int n = pg >> 3, k = pg & 7;
                float4 x4 = *(const float4*)&kv_s[n][k][i];
                ak[p] += wk4.x * x4.x + wk4.y * x4.y + wk4.z * x4.z + wk4.w * x4.w;
                av[p] += wv4.x * x4.x + wv4.y * x4.y + wv4.z * x4.z + wv4.w * x4.w;
            }
        }
        #pragma unroll
        for (int p = 0; p < 16; ++p) {
            int pg = layer * 16 + p;
            int n = pg >> 3, k = pg & 7;
            kh_s[n][k][d] = ak[p];
            vh_s[n][k][d] = av[p];
        }
    }
    __syncthreads();
    {   // scores + softmax + ctx
        int n = tid >> 6, lane = tid & 63;
        int dh = lane & 31, hh = lane >> 5;
        #pragma unroll
        for (int hp = 0; hp < 2; ++hp) {
            int h = hp * 2 + hh;
            int dd0 = h * 32 + dh;
            float qv = qh_s[n][dd0];
            float sc[8];
            #pragma unroll
            for (int k = 0; k < 8; ++k) {
                float p = qv * kh_s[n][k][dd0];
                #pragma unroll
                for (int msk = 16; msk >= 1; msk >>= 1) p += __shfl_xor(p, msk, 32);
                sc[k] = p * 0.17677669529663687f;
            }
            float mx = sc[0];
            #pragma unroll
            for (int k = 1; k < 8; ++k) mx = fmaxf(mx, sc[k]);
            float den = 0.f;
            #pragma unroll
            for (int k = 0; k < 8; ++k) { sc[k] = expf(sc[k] - mx); den += sc[k]; }
            float inv = 1.0f / den;
            float c = 0.f;
            #pragma unroll
            for (int k = 0; k < 8; ++k) c += sc[k] * vh_s[n][k][dd0];
            ctx_s[n][dd0] = c * inv;
        }
    }
    __syncthreads();
    {   // out_proj
        int d = tid & 127, half = tid >> 7;
        for (int n2 = 0; n2 < 2; ++n2) {
            int n = half * 2 + n2;
            float a = ob[d];
            const float* wr = ow + (size_t)d * 128;
            #pragma unroll
            for (int i = 0; i < 128; i += 4) {
                float4 w4 = *(const float4*)(wr + i);
                a += w4.x * ctx_s[n][i] + w4.y * ctx_s[n][i + 1] + w4.z * ctx_s[n][i + 2] + w4.w * ctx_s[n][i + 3];
            }
            o1_s[n][d] = a;
        }
    }
    __syncthreads();
    {   // final proj
        int d = tid & 127, half = tid >> 7;
        for (int n2 = 0; n2 < 2; ++n2) {
            int n = half * 2 + n2;
            float a = pb[d];
            const float* wr = pw + (size_t)d * 128;
            #pragma unroll
            for (int i = 0; i < 128; i += 4) {
                float4 w4 = *(const float4*)(wr + i);
                a += w4.x * o1_s[n][i] + w4.y * o1_s[n][i + 1] + w4.z * o1_s[n][i + 2] + w4.w * o1_s[n][i + 3];
            }
            out[(size_t)(b * NN + n0 + n) * 128 + d] = a;
        }
    }
}

extern "C" void kernel_launch(void* const* d_in, const int* in_sizes, int n_in,
                              void* d_out, int out_size, void* d_ws, size_t ws_size,
                              hipStream_t stream) {
    const float* x_scalar   = (const float*)d_in[0];
    const int*   season_q   = (const int*)d_in[1];
    const float* year_q     = (const float*)d_in[2];
    const float* dw_w       = (const float*)d_in[3];
    const float* dw_b       = (const float*)d_in[4];
    const float* pw_w       = (const float*)d_in[5];
    const float* pw_b       = (const float*)d_in[6];
    const float* ln_g       = (const float*)d_in[7];
    const float* ln_bb      = (const float*)d_in[8];
    const float* in_proj_w  = (const float*)d_in[9];
    const float* in_proj_b  = (const float*)d_in[10];
    const float* out_proj_w = (const float*)d_in[11];
    const float* out_proj_b = (const float*)d_in[12];
    const float* proj_w     = (const float*)d_in[13];
    const float* proj_b     = (const float*)d_in[14];
    const float* memory_bank= (const float*)d_in[15];
    const int*   mem_season = (const int*)d_in[16];
    const float* mem_year   = (const float*)d_in[17];

    float* out_final = (float*)d_out;
    float* q_out = out_final + (size_t)BB_ * NN * DD;

    float* ws = (float*)d_ws;
    float* XC    = ws;                      // 1,048,576 floats
    float* QPRE  = XC + 1048576;            // 1,048,576
    float* QNORM = QPRE + 1048576;          // 16
    float* NRMP  = QNORM + 16;              // 4*MM
    float* SIMP  = NRMP + 4 * MM;           // 64*MM
    int*   TOPK  = (int*)(SIMP + 64 * MM);  // 128

    k1_conv<<<dim3(8, 16), 256, 0, stream>>>(x_scalar, dw_w, dw_b, XC);
    k2_pw<<<dim3(512, 16), 256, 0, stream>>>(pw_w, pw_b, XC, QPRE);
    k3_ln<<<2048, 256, 0, stream>>>(QPRE, ln_g, ln_bb, q_out);
    k3b_qnorm<<<16, 256, 0, stream>>>(q_out, QNORM);
    k4_sim<<<dim3(299, 4), 256, 0, stream>>>(memory_bank, q_out, SIMP, NRMP);
    k5_topk<<<16, 256, 0, stream>>>(SIMP, NRMP, QNORM, season_q, year_q, mem_season, mem_year, TOPK);
    k6_attn<<<dim3(128, 16), 256, 0, stream>>>(memory_bank, q_out, TOPK, in_proj_w, in_proj_b,
                                               out_proj_w, out_proj_b, proj_w, proj_b, out_final);
}

// Round 3
// 1125.648 us; speedup vs baseline: 1.9022x; 1.9022x over previous
//
#include <hip/hip_runtime.h>
#include <hip/hip_bf16.h>

#define BB_ 16
#define TT_ 96
#define NN 512
#define DD 128
#define MM 1196
#define KK 8
#define HID 65536
#define TP 97
#define TPAD 128

typedef __attribute__((ext_vector_type(8))) short short8v;
typedef __attribute__((ext_vector_type(4))) float f32x4;

__device__ __forceinline__ float gelu_exact(float x) {
    return 0.5f * x * (1.0f + erff(x * 0.70710678118654752f));
}
__device__ __forceinline__ unsigned rne16(float f) {
    unsigned u = __float_as_uint(f);
    return (u + 0x7fffu + ((u >> 16) & 1u)) >> 16;
}
// split f32 -> bf16 hi + bf16 lo (hi = rne(x), lo = rne(x - hi))
__device__ __forceinline__ void split2(float x, short& hi, short& lo) {
    unsigned h = rne16(x);
    hi = (short)h;
    float hf = __uint_as_float(h << 16);
    lo = (short)rne16(x - hf);
}
__device__ __forceinline__ void gload_lds16(const void* g, void* l) {
    __builtin_amdgcn_global_load_lds((const __attribute__((address_space(1))) void*)g,
                                     (__attribute__((address_space(3))) void*)l, 16, 0, 0);
}

// K0: pw_w f32 -> (hi, lo) bf16 pair
__global__ __launch_bounds__(256) void k0_cvt2(const float* __restrict__ src,
                                               short* __restrict__ hi, short* __restrict__ lo) {
    size_t i = ((size_t)blockIdx.x * 256 + threadIdx.x) * 8;
    float4 a = *(const float4*)(src + i);
    float4 b = *(const float4*)(src + i + 4);
    short h[8], l[8];
    split2(a.x, h[0], l[0]); split2(a.y, h[1], l[1]);
    split2(a.z, h[2], l[2]); split2(a.w, h[3], l[3]);
    split2(b.x, h[4], l[4]); split2(b.y, h[5], l[5]);
    split2(b.z, h[6], l[6]); split2(b.w, h[7], l[7]);
    *(short8v*)(hi + i) = *(short8v*)h;
    *(short8v*)(lo + i) = *(short8v*)l;
}

// K1: depthwise conv + bias + exact gelu -> xct hi/lo bf16, layout [b][t][n], zero-padded t>=97
__global__ __launch_bounds__(256) void k1_conv(const float* __restrict__ x,
                                               const float* __restrict__ dw_w,
                                               const float* __restrict__ dw_b,
                                               short* __restrict__ xh,
                                               short* __restrict__ xl) {
    int b = blockIdx.y, n0 = blockIdx.x * 64;
    __shared__ float xs[96][64];
    __shared__ float ws[64][12];
    __shared__ float bs[64];
    int tid = threadIdx.x;
    for (int j = tid; j < 96 * 64; j += 256) {
        int t = j / 64, n = j % 64;
        xs[t][n] = x[(size_t)(b * TT_ + t) * NN + n0 + n];
    }
    for (int j = tid; j < 64 * 12; j += 256) {
        int n = j / 12, k = j % 12;
        ws[n][k] = dw_w[(size_t)(n0 + n) * 12 + k];
    }
    if (tid < 64) bs[tid] = dw_b[n0 + tid];
    __syncthreads();
    int n = tid % 64, g = tid / 64;
    for (int t = g; t < TP; t += 4) {
        float acc = bs[n];
        #pragma unroll
        for (int k = 0; k < 12; ++k) {
            int ti = t - 6 + k;
            if (ti >= 0 && ti < 96) acc += xs[ti][n] * ws[n][k];
        }
        float v = gelu_exact(acc);
        short h, l;
        split2(v, h, l);
        size_t idx = ((size_t)b * TPAD + t) * NN + n0 + n;
        xh[idx] = h; xl[idx] = l;
    }
    for (int t = TP + g; t < TPAD; t += 4) {
        size_t idx = ((size_t)b * TPAD + t) * NN + n0 + n;
        xh[idx] = 0; xl[idx] = 0;
    }
}

// K2: split-bf16 3-pass MFMA GEMM. C = pw_w(65536x512) @ xct^T(512x128) per b,
// fused bias + exact gelu + masked mean over t<97 -> q_pre.
// 128x128 tile, BK=64, 4 waves 2x2. LDS tiles XOR-swizzled (chunk ^= row&7, 16B chunks).
// PRE: A staged via global_load_lds from pre-split aH/aL (pre-swizzled source).
// !PRE: A reg-staged from f32 pw_w with on-the-fly split (swizzled ds_write).
template <bool PRE>
__global__ __launch_bounds__(256) void k2_split(const float* __restrict__ pw_w,
                                                const short* __restrict__ aH,
                                                const short* __restrict__ aL,
                                                const float* __restrict__ pw_b,
                                                const short* __restrict__ bH,
                                                const short* __restrict__ bL,
                                                float* __restrict__ q_pre) {
    int b = blockIdx.y;
    int o0 = blockIdx.x * 128;
    __shared__ short AsH[8192], AsL[8192], BsH[8192], BsL[8192];
    __shared__ float red[128][2];
    int tid = threadIdx.x;
    int l = tid & 63, w = tid >> 6;
    int wr = w >> 1, wc = w & 1;
    int lrow = l & 15, lk = l >> 4;
    const short* bHb = bH + (size_t)b * TPAD * NN;
    const short* bLb = bL + (size_t)b * TPAD * NN;

    f32x4 acc[4][4];
    #pragma unroll
    for (int m = 0; m < 4; ++m)
        #pragma unroll
        for (int n = 0; n < 4; ++n) acc[m][n] = (f32x4){0.f, 0.f, 0.f, 0.f};

    int srow = tid >> 3;        // 0..31 (row within c-group)
    int cc = tid & 7;           // 16B chunk index within 64-elem row
    for (int it = 0; it < 8; ++it) {
        int k0 = it * 64;
        int scc = cc ^ (srow & 7);  // pre-swizzled source chunk (r&7 == srow&7 since c*32 % 8 == 0)
        #pragma unroll
        for (int c = 0; c < 4; ++c) {
            int r = c * 32 + srow;
            gload_lds16(bHb + (size_t)r * NN + k0 + scc * 8, &BsH[c * 2048 + tid * 8]);
            gload_lds16(bLb + (size_t)r * NN + k0 + scc * 8, &BsL[c * 2048 + tid * 8]);
        }
        if constexpr (PRE) {
            #pragma unroll
            for (int c = 0; c < 4; ++c) {
                int r = c * 32 + srow;
                gload_lds16(aH + (size_t)(o0 + r) * 512 + k0 + scc * 8, &AsH[c * 2048 + tid * 8]);
                gload_lds16(aL + (size_t)(o0 + r) * 512 + k0 + scc * 8, &AsL[c * 2048 + tid * 8]);
            }
        } else {
            #pragma unroll
            for (int c = 0; c < 4; ++c) {
                int r = c * 32 + srow;
                const float* src = pw_w + (size_t)(o0 + r) * 512 + k0 + cc * 8;
                float4 v0 = *(const float4*)(src);
                float4 v1 = *(const float4*)(src + 4);
                short h[8], lo[8];
                split2(v0.x, h[0], lo[0]); split2(v0.y, h[1], lo[1]);
                split2(v0.z, h[2], lo[2]); split2(v0.w, h[3], lo[3]);
                split2(v1.x, h[4], lo[4]); split2(v1.y, h[5], lo[5]);
                split2(v1.z, h[6], lo[6]); split2(v1.w, h[7], lo[7]);
                int didx = r * 64 + (cc ^ (r & 7)) * 8;
                *(short8v*)&AsH[didx] = *(short8v*)h;
                *(short8v*)&AsL[didx] = *(short8v*)lo;
            }
        }
        __syncthreads();
        #pragma unroll
        for (int kk = 0; kk < 2; ++kk) {
            short8v ah[4], al[4], bh[4], bl[4];
            #pragma unroll
            for (int m = 0; m < 4; ++m) {
                int row = wr * 64 + m * 16 + lrow;
                int idx = row * 64 + ((kk * 4 + lk) ^ (row & 7)) * 8;
                ah[m] = *(const short8v*)&AsH[idx];
                al[m] = *(const short8v*)&AsL[idx];
            }
            #pragma unroll
            for (int n = 0; n < 4; ++n) {
                int row = wc * 64 + n * 16 + lrow;
                int idx = row * 64 + ((kk * 4 + lk) ^ (row & 7)) * 8;
                bh[n] = *(const short8v*)&BsH[idx];
                bl[n] = *(const short8v*)&BsL[idx];
            }
            #pragma unroll
            for (int m = 0; m < 4; ++m)
                #pragma unroll
                for (int n = 0; n < 4; ++n) {
                    acc[m][n] = __builtin_amdgcn_mfma_f32_16x16x32_bf16(ah[m], bh[n], acc[m][n], 0, 0, 0);
                    acc[m][n] = __builtin_amdgcn_mfma_f32_16x16x32_bf16(ah[m], bl[n], acc[m][n], 0, 0, 0);
                    acc[m][n] = __builtin_amdgcn_mfma_f32_16x16x32_bf16(al[m], bh[n], acc[m][n], 0, 0, 0);
                }
        }
        __syncthreads();
    }
    // epilogue: bias + exact gelu + mask t<97 + mean over t
    #pragma unroll
    for (int m = 0; m < 4; ++m) {
        #pragma unroll
        for (int reg = 0; reg < 4; ++reg) {
            int o_loc = wr * 64 + m * 16 + lk * 4 + reg;
            float bias = pw_b[o0 + o_loc];
            float s = 0.f;
            #pragma unroll
            for (int n = 0; n < 4; ++n) {
                int t = wc * 64 + n * 16 + lrow;
                if (t < TP) s += gelu_exact(acc[m][n][reg] + bias);
            }
            s += __shfl_xor(s, 1, 64);
            s += __shfl_xor(s, 2, 64);
            s += __shfl_xor(s, 4, 64);
            s += __shfl_xor(s, 8, 64);
            if (lrow == 0) red[o_loc][wc] = s;
        }
    }
    __syncthreads();
    if (tid < 128)
        q_pre[(size_t)b * HID + o0 + tid] = (red[tid][0] + red[tid][1]) * (1.0f / 97.0f);
}

// K3: LayerNorm over D=128 per row; writes q (second output)
__global__ __launch_bounds__(256) void k3_ln(const float* __restrict__ q_pre,
                                             const float* __restrict__ g,
                                             const float* __restrict__ beta,
                                             float* __restrict__ qout) {
    int row = blockIdx.x * 4 + (threadIdx.x >> 6);
    int lane = threadIdx.x & 63;
    const float* src = q_pre + (size_t)row * 128;
    float v0 = src[lane], v1 = src[lane + 64];
    float s = v0 + v1;
    #pragma unroll
    for (int m = 32; m >= 1; m >>= 1) s += __shfl_xor(s, m, 64);
    float mu = s * (1.f / 128.f);
    float d0 = v0 - mu, d1 = v1 - mu;
    float vs = d0 * d0 + d1 * d1;
    #pragma unroll
    for (int m = 32; m >= 1; m >>= 1) vs += __shfl_xor(vs, m, 64);
    float rstd = rsqrtf(vs * (1.f / 128.f) + 1e-5f);
    qout[(size_t)row * 128 + lane] = d0 * rstd * g[lane] + beta[lane];
    qout[(size_t)row * 128 + lane + 64] = d1 * rstd * g[lane + 64] + beta[lane + 64];
}

// K3b: per-b L2 norm of q
__global__ __launch_bounds__(256) void k3b_qnorm(const float* __restrict__ q, float* __restrict__ qnorm) {
    int b = blockIdx.x;
    const float* src = q + (size_t)b * HID;
    float s = 0.f;
    for (int i = threadIdx.x * 4; i < HID; i += 256 * 4) {
        float4 v = *(const float4*)(src + i);
        s += v.x * v.x + v.y * v.y + v.z * v.z + v.w * v.w;
    }
    #pragma unroll
    for (int m = 32; m >= 1; m >>= 1) s += __shfl_xor(s, m, 64);
    __shared__ float red[4];
    if ((threadIdx.x & 63) == 0) red[threadIdx.x >> 6] = s;
    __syncthreads();
    if (threadIdx.x == 0) qnorm[b] = sqrtf(red[0] + red[1] + red[2] + red[3]);
}

// K4: fused (mem row sumsq) + (16 q-dots), deterministic K-split partials
__global__ __launch_bounds__(256) void k4_sim(const float* __restrict__ mem,
                                              const float* __restrict__ q,
                                              float* __restrict__ sim_part,
                                              float* __restrict__ nrm_part) {
    int m0 = blockIdx.x * 4;
    int isp = blockIdx.y;
    int tid = threadIdx.x;
    float acc[4][16];
    float nr[4] = {0.f, 0.f, 0.f, 0.f};
    #pragma unroll
    for (int a = 0; a < 4; ++a)
        #pragma unroll
        for (int c = 0; c < 16; ++c) acc[a][c] = 0.f;
    int ibase = isp * 16384;
    for (int it = 0; it < 16; ++it) {
        int i = ibase + (it * 256 + tid) * 4;
        float4 mv[4];
        #pragma unroll
        for (int a = 0; a < 4; ++a) {
            mv[a] = *(const float4*)(mem + (size_t)(m0 + a) * HID + i);
            nr[a] += mv[a].x * mv[a].x + mv[a].y * mv[a].y + mv[a].z * mv[a].z + mv[a].w * mv[a].w;
        }
        #pragma unroll
        for (int c = 0; c < 16; ++c) {
            float4 qv = *(const float4*)(q + (size_t)c * HID + i);
            #pragma unroll
            for (int a = 0; a < 4; ++a)
                acc[a][c] += mv[a].x * qv.x + mv[a].y * qv.y + mv[a].z * qv.z + mv[a].w * qv.w;
        }
    }
    __shared__ float red[4][68];
    int wv = tid >> 6, lane = tid & 63;
    #pragma unroll
    for (int a = 0; a < 4; ++a)
        for (int c = 0; c < 17; ++c) {
            float v = (c < 16) ? acc[a][c] : nr[a];
            #pragma unroll
            for (int m = 32; m >= 1; m >>= 1) v += __shfl_xor(v, m, 64);
            if (lane == 0) red[wv][a * 17 + c] = v;
        }
    __syncthreads();
    if (tid < 68) {
        float v = red[0][tid] + red[1][tid] + red[2][tid] + red[3][tid];
        int a = tid / 17, r = tid % 17;
        if (r < 16) sim_part[((size_t)isp * 16 + r) * MM + m0 + a] = v;
        else nrm_part[(size_t)isp * MM + m0 + a] = v;
    }
}

// K5: combine, normalize, mask, diversity, top-8 (tie -> lower index)
__global__ __launch_bounds__(256) void k5_topk(const float* __restrict__ sim_part,
                                               const float* __restrict__ nrm_part,
                                               const float* __restrict__ qnorm,
                                               const int* __restrict__ season_q,
                                               const float* __restrict__ year_q,
                                               const int* __restrict__ mem_season,
                                               const float* __restrict__ mem_year,
                                               int* __restrict__ topk) {
    int b = blockIdx.x;
    int tid = threadIdx.x;
    __shared__ float sadj[MM];
    float nq = fmaxf(qnorm[b], 1e-12f);
    int sq = season_q[b];
    float yq = year_q[b];
    for (int m = tid; m < MM; m += 256) {
        float dot = 0.f, ns = 0.f;
        #pragma unroll
        for (int p = 0; p < 4; ++p) {
            dot += sim_part[((size_t)p * 16 + b) * MM + m];
            ns += nrm_part[(size_t)p * MM + m];
        }
        float nm = fmaxf(sqrtf(ns), 1e-12f);
        float s = dot / (nq * nm);
        if (mem_season[m] != sq) s = -10000.0f;
        float dy = fabsf(yq - mem_year[m]);
        float dv = 1.0f - expf(-dy * 0.5f);
        s *= (0.5f + 0.5f * dv);
        sadj[m] = s;
    }
    __syncthreads();
    __shared__ float rv[4];
    __shared__ int ri[4];
    for (int it = 0; it < 8; ++it) {
        float bv = -INFINITY;
        int bi = -1;
        for (int m = tid; m < MM; m += 256) {
            float v = sadj[m];
            if (v > bv || (v == bv && bi >= 0 && m < bi)) { bv = v; bi = m; }
        }
        #pragma unroll
        for (int msk = 32; msk >= 1; msk >>= 1) {
            float ov = __shfl_xor(bv, msk, 64);
            int oi = __shfl_xor(bi, msk, 64);
            if (oi >= 0 && (ov > bv || (ov == bv && (bi < 0 || oi < bi)))) { bv = ov; bi = oi; }
        }
        int lane = tid & 63, wv = tid >> 6;
        if (lane == 0) { rv[wv] = bv; ri[wv] = bi; }
        __syncthreads();
        if (tid == 0) {
            float fv = rv[0]; int fi = ri[0];
            for (int w = 1; w < 4; ++w)
                if (ri[w] >= 0 && (rv[w] > fv || (rv[w] == fv && (fi < 0 || ri[w] < fi)))) { fv = rv[w]; fi = ri[w]; }
            topk[b * KK + it] = fi;
            sadj[fi] = -INFINITY;
        }
        __syncthreads();
    }
}

// K6: fused attention
__global__ __launch_bounds__(256) void k6_attn(const float* __restrict__ mem,
                                               const float* __restrict__ q,
                                               const int* __restrict__ topk,
                                               const float* __restrict__ in_w,
                                               const float* __restrict__ in_b,
                                               const float* __restrict__ ow,
                                               const float* __restrict__ ob,
                                               const float* __restrict__ pw,
                                               const float* __restrict__ pb,
                                               float* __restrict__ out) {
    int b = blockIdx.y;
    int n0 = blockIdx.x * 4;
    int tid = threadIdx.x;
    __shared__ float kv_s[4][8][128];
    __shared__ float kh_s[4][8][128];
    __shared__ float vh_s[4][8][128];
    __shared__ float qin_s[4][128];
    __shared__ float qh_s[4][128];
    __shared__ float ctx_s[4][128];
    __shared__ float o1_s[4][128];
    __shared__ int idx_s[8];
    if (tid < 8) idx_s[tid] = topk[b * 8 + tid];
    __syncthreads();
    for (int j = tid; j < 4 * 8 * 32; j += 256) {
        int n = j >> 8;
        int k = (j >> 5) & 7;
        int d4 = (j & 31) * 4;
        float4 v = *(const float4*)(mem + (size_t)idx_s[k] * HID + (size_t)(n0 + n) * 128 + d4);
        *(float4*)&kv_s[n][k][d4] = v;
    }
    for (int j = tid; j < 4 * 32; j += 256) {
        int n = j >> 5;
        int d4 = (j & 31) * 4;
        *(float4*)&qin_s[n][d4] = *(const float4*)(q + (size_t)(b * NN + n0 + n) * 128 + d4);
    }
    __syncthreads();
    {
        int d = tid & 127, half = tid >> 7;
        for (int n2 = 0; n2 < 2; ++n2) {
            int n = half * 2 + n2;
            float a = in_b[d];
            const float* wr = in_w + (size_t)d * 128;
            #pragma unroll
            for (int i = 0; i < 128; i += 4) {
                float4 w4 = *(const float4*)(wr + i);
                a += w4.x * qin_s[n][i] + w4.y * qin_s[n][i + 1] + w4.z * qin_s[n][i + 2] + w4.w * qin_s[n][i + 3];
            }
            qh_s[n][d] = a;
        }
    }
    {
        int d = tid & 127, layer = tid >> 7;
        float ak[16], av[16];
        #pragma unroll
        for (int p = 0; p < 16; ++p) { ak[p] = in_b[128 + d]; av[p] = in_b[256 + d]; }
        const float* wkr = in_w + (size_t)(128 + d) * 128;
        const float* wvr = in_w + (size_t)(256 + d) * 128;
        for (int i = 0; i < 128; i += 4) {
            float4 wk4 = *(const float4*)(wkr + i);
            float4 wv4 = *(const float4*)(wvr + i);
            #pragma unroll
            for (int p = 0; p < 16; ++p) {
                int pg = layer * 16 + p;
                int n = pg >> 3, k = pg & 7;
                float4 x4 = *(const float4*)&kv_s[n][k][i];
                ak[p] += wk4.x * x4.x + wk4.y * x4.y + wk4.z * x4.z + wk4.w * x4.w;
                av[p] += wv4.x * x4.x + wv4.y * x4.y + wv4.z * x4.z + wv4.w * x4.w;
            }
        }
        #pragma unroll
        for (int p = 0; p < 16; ++p) {
            int pg = layer * 16 + p;
            int n = pg >> 3, k = pg & 7;
            kh_s[n][k][d] = ak[p];
            vh_s[n][k][d] = av[p];
        }
    }
    __syncthreads();
    {
        int n = tid >> 6, lane = tid & 63;
        int dh = lane & 31, hh = lane >> 5;
        #pragma unroll
        for (int hp = 0; hp < 2; ++hp) {
            int h = hp * 2 + hh;
            int dd0 = h * 32 + dh;
            float qv = qh_s[n][dd0];
            float sc[8];
            #pragma unroll
            for (int k = 0; k < 8; ++k) {
                float p = qv * kh_s[n][k][dd0];
                #pragma unroll
                for (int msk = 16; msk >= 1; msk >>= 1) p += __shfl_xor(p, msk, 32);
                sc[k] = p * 0.17677669529663687f;
            }
            float mx = sc[0];
            #pragma unroll
            for (int k = 1; k < 8; ++k) mx = fmaxf(mx, sc[k]);
            float den = 0.f;
            #pragma unroll
            for (int k = 0; k < 8; ++k) { sc[k] = expf(sc[k] - mx); den += sc[k]; }
            float inv = 1.0f / den;
            float c = 0.f;
            #pragma unroll
            for (int k = 0; k < 8; ++k) c += sc[k] * vh_s[n][k][dd0];
            ctx_s[n][dd0] = c * inv;
        }
    }
    __syncthreads();
    {
        int d = tid & 127, half = tid >> 7;
        for (int n2 = 0; n2 < 2; ++n2) {
            int n = half * 2 + n2;
            float a = ob[d];
            const float* wr = ow + (size_t)d * 128;
            #pragma unroll
            for (int i = 0; i < 128; i += 4) {
                float4 w4 = *(const float4*)(wr + i);
                a += w4.x * ctx_s[n][i] + w4.y * ctx_s[n][i + 1] + w4.z * ctx_s[n][i + 2] + w4.w * ctx_s[n][i + 3];
            }
            o1_s[n][d] = a;
        }
    }
    __syncthreads();
    {
        int d = tid & 127, half = tid >> 7;
        for (int n2 = 0; n2 < 2; ++n2) {
            int n = half * 2 + n2;
            float a = pb[d];
            const float* wr = pw + (size_t)d * 128;
            #pragma unroll
            for (int i = 0; i < 128; i += 4) {
                float4 w4 = *(const float4*)(wr + i);
                a += w4.x * o1_s[n][i] + w4.y * o1_s[n][i + 1] + w4.z * o1_s[n][i + 2] + w4.w * o1_s[n][i + 3];
            }
            out[(size_t)(b * NN + n0 + n) * 128 + d] = a;
        }
    }
}

extern "C" void kernel_launch(void* const* d_in, const int* in_sizes, int n_in,
                              void* d_out, int out_size, void* d_ws, size_t ws_size,
                              hipStream_t stream) {
    const float* x_scalar   = (const float*)d_in[0];
    const int*   season_q   = (const int*)d_in[1];
    const float* year_q     = (const float*)d_in[2];
    const float* dw_w       = (const float*)d_in[3];
    const float* dw_b       = (const float*)d_in[4];
    const float* pw_w       = (const float*)d_in[5];
    const float* pw_b       = (const float*)d_in[6];
    const float* ln_g       = (const float*)d_in[7];
    const float* ln_bb      = (const float*)d_in[8];
    const float* in_proj_w  = (const float*)d_in[9];
    const float* in_proj_b  = (const float*)d_in[10];
    const float* out_proj_w = (const float*)d_in[11];
    const float* out_proj_b = (const float*)d_in[12];
    const float* proj_w     = (const float*)d_in[13];
    const float* proj_b     = (const float*)d_in[14];
    const float* memory_bank= (const float*)d_in[15];
    const int*   mem_season = (const int*)d_in[16];
    const float* mem_year   = (const float*)d_in[17];

    float* out_final = (float*)d_out;
    float* q_out = out_final + (size_t)BB_ * NN * DD;

    float* ws = (float*)d_ws;
    size_t off = 0;
    float* QPRE  = ws + off; off += 1048576;
    float* QNORM = ws + off; off += 16;
    float* NRMP  = ws + off; off += 4 * MM;
    float* SIMP  = ws + off; off += 64 * MM;
    int*   TOPK  = (int*)(ws + off); off += 128;
    short* XH    = (short*)(ws + off); off += 524288;   // 1,048,576 bf16
    short* XL    = (short*)(ws + off); off += 524288;
    size_t base_off = off;
    short* AH    = (short*)(ws + off); off += 16777216; // 33,554,432 bf16
    short* AL    = (short*)(ws + off); off += 16777216;
    bool use_pre = (ws_size >= off * 4);
    (void)base_off;

    k1_conv<<<dim3(8, 16), 256, 0, stream>>>(x_scalar, dw_w, dw_b, XH, XL);
    if (use_pre) {
        k0_cvt2<<<16384, 256, 0, stream>>>(pw_w, AH, AL);
        k2_split<true><<<dim3(512, 16), 256, 0, stream>>>(pw_w, AH, AL, pw_b, XH, XL, QPRE);
    } else {
        k2_split<false><<<dim3(512, 16), 256, 0, stream>>>(pw_w, nullptr, nullptr, pw_b, XH, XL, QPRE);
    }
    k3_ln<<<2048, 256, 0, stream>>>(QPRE, ln_g, ln_bb, q_out);
    k3b_qnorm<<<16, 256, 0, stream>>>(q_out, QNORM);
    k4_sim<<<dim3(299, 4), 256, 0, stream>>>(memory_bank, q_out, SIMP, NRMP);
    k5_topk<<<16, 256, 0, stream>>>(SIMP, NRMP, QNORM, season_q, year_q, mem_season, mem_year, TOPK);
    k6_attn<<<dim3(128, 16), 256, 0, stream>>>(memory_bank, q_out, TOPK, in_proj_w, in_proj_b,
                                               out_proj_w, out_proj_b, proj_w, proj_b, out_final);
}